// Round 1
// baseline (349.049 us; speedup 1.0000x reference)
//
#include <hip/hip_runtime.h>
#include <hip/hip_bf16.h>

#define M_DIM 64
#define K_DIM 4096
#define N_DIM 14336
#define TN 32
#define TK 64
#define KITERS (K_DIM / TK)  // 64

typedef __attribute__((ext_vector_type(8))) short bf16x8;
typedef __attribute__((ext_vector_type(4))) float f32x4;

// ---------------------------------------------------------------------------
// prep: split x (fp32) into bf16 hi/lo pair, stored in MFMA-A-fragment-
// friendly permuted layout: idx = (k/8)*(64*8) + m*8 + (k%8).
// Each thread handles one (kb, m) group of 8 consecutive k -> 16B writes.
__global__ void prep_split(const float* __restrict__ x,
                           __hip_bfloat16* __restrict__ xh,
                           __hip_bfloat16* __restrict__ xl) {
  int tg = blockIdx.x * blockDim.x + threadIdx.x;  // 0..32767
  int m = tg & 63;
  int kb = tg >> 6;  // 0..511
  const float* xp = x + m * K_DIM + kb * 8;
  int o = kb * (M_DIM * 8) + m * 8;
#pragma unroll
  for (int j = 0; j < 8; ++j) {
    float v = xp[j];
    __hip_bfloat16 h = __float2bfloat16(v);
    float r = v - __bfloat162float(h);
    xh[o + j] = h;
    xl[o + j] = __float2bfloat16(r);
  }
}

// rowsum(x) per row m (needed for the offset term)
__global__ void rowsum_k(const float* __restrict__ x, float* __restrict__ rs) {
  int m = blockIdx.x;
  int t = threadIdx.x;
  float s = 0.f;
  for (int k = t; k < K_DIM; k += 256) s += x[m * K_DIM + k];
#pragma unroll
  for (int off = 32; off > 0; off >>= 1) s += __shfl_down(s, off, 64);
  __shared__ float red[4];
  if ((t & 63) == 0) red[t >> 6] = s;
  __syncthreads();
  if (t == 0) rs[m] = red[0] + red[1] + red[2] + red[3];
}

// ---------------------------------------------------------------------------
// Main kernel: block computes 64(M) x 32(N) tile over full K.
// W tile (64k x 32n int32) staged via regs -> cvt bf16 -> LDS (double buffer).
// LDS layout: bsh[buf][n][k] with k-row padded 64->72 (stride 144B, 16B-aligned)
// so frag ds_read_b128 is ~2-way (free) and b16 writes are tolerable.
__global__ __launch_bounds__(256) void wqmm(
    const int* __restrict__ W, const __hip_bfloat16* __restrict__ xh,
    const __hip_bfloat16* __restrict__ xl, const float* __restrict__ rowsum,
    const float* __restrict__ scale, const float* __restrict__ offset,
    const float* __restrict__ bias, float* __restrict__ out) {
  __shared__ __align__(16) unsigned short bsh[2][TN][72];

  const int t = threadIdx.x;
  const int lane = t & 63;
  const int wv = t >> 6;       // wave id 0..3 -> m group
  const int quad = lane >> 4;  // 0..3
  const int lnk = lane & 15;
  const int nblk = blockIdx.x * TN;

  f32x4 acc0 = {0.f, 0.f, 0.f, 0.f};
  f32x4 acc1 = {0.f, 0.f, 0.f, 0.f};

  // staging mapping: idx in [0,512): kl = idx>>3 (k row 0..63), nl = (idx&7)*4
  const int kl0 = t >> 3;
  const int kl1 = kl0 + 32;
  const int nl = (t & 7) * 4;

  int4 wreg[2];

  const int mrow = wv * 16 + lnk;
  const __hip_bfloat16* xh_m = xh + mrow * 8;
  const __hip_bfloat16* xl_m = xl + mrow * 8;

#define STAGE_LOAD(k0)                                                      \
  do {                                                                      \
    wreg[0] = *(const int4*)(W + (size_t)((k0) + kl0) * N_DIM + nblk + nl); \
    wreg[1] = *(const int4*)(W + (size_t)((k0) + kl1) * N_DIM + nblk + nl); \
  } while (0)

#define STAGE_WRITE(p)                                              \
  do {                                                              \
    _Pragma("unroll") for (int c = 0; c < 2; ++c) {                 \
      int kl = c ? kl1 : kl0;                                       \
      int vals[4] = {wreg[c].x, wreg[c].y, wreg[c].z, wreg[c].w};   \
      _Pragma("unroll") for (int i = 0; i < 4; ++i) {               \
        float f = (float)vals[i]; /* exact: |w|<=128 */             \
        bsh[p][nl + i][kl] =                                        \
            (unsigned short)(__float_as_uint(f) >> 16); /* exact */ \
      }                                                             \
    }                                                               \
  } while (0)

  STAGE_LOAD(0);
  STAGE_WRITE(0);
  int p = 0;

  for (int it = 0; it < KITERS; ++it) {
    __syncthreads();
    if (it + 1 < KITERS) STAGE_LOAD((it + 1) * TK);

    const int kb0 = it * (TK / 8);
#pragma unroll
    for (int ks = 0; ks < 2; ++ks) {
      const int kb = kb0 + ks * 4 + quad;
      bf16x8 ah = *(const bf16x8*)(xh_m + kb * (M_DIM * 8));
      bf16x8 al = *(const bf16x8*)(xl_m + kb * (M_DIM * 8));
      bf16x8 b0 = *(const bf16x8*)&bsh[p][lnk][ks * 32 + quad * 8];
      bf16x8 b1 = *(const bf16x8*)&bsh[p][16 + lnk][ks * 32 + quad * 8];
      acc0 = __builtin_amdgcn_mfma_f32_16x16x32_bf16(ah, b0, acc0, 0, 0, 0);
      acc0 = __builtin_amdgcn_mfma_f32_16x16x32_bf16(al, b0, acc0, 0, 0, 0);
      acc1 = __builtin_amdgcn_mfma_f32_16x16x32_bf16(ah, b1, acc1, 0, 0, 0);
      acc1 = __builtin_amdgcn_mfma_f32_16x16x32_bf16(al, b1, acc1, 0, 0, 0);
    }

    if (it + 1 < KITERS) STAGE_WRITE(p ^ 1);
    p ^= 1;
  }

  // epilogue: out = scale*acc + scale*offset*rowsum[m] + bias
#pragma unroll
  for (int nbi = 0; nbi < 2; ++nbi) {
    int n = nblk + nbi * 16 + lnk;
    float s = scale[n];
    float so = s * offset[n];
    float bi = bias[n];
    f32x4 a = nbi ? acc1 : acc0;
#pragma unroll
    for (int r = 0; r < 4; ++r) {
      int m = wv * 16 + quad * 4 + r;  // C/D: col=lane&15, row=quad*4+reg
      out[(size_t)m * N_DIM + n] = a[r] * s + so * rowsum[m] + bi;
    }
  }
}

extern "C" void kernel_launch(void* const* d_in, const int* in_sizes, int n_in,
                              void* d_out, int out_size, void* d_ws,
                              size_t ws_size, hipStream_t stream) {
  const float* x = (const float*)d_in[0];
  const int* W = (const int*)d_in[1];
  const float* scale = (const float*)d_in[2];
  const float* offset = (const float*)d_in[3];
  const float* bias = (const float*)d_in[4];
  float* out = (float*)d_out;

  __hip_bfloat16* xh = (__hip_bfloat16*)d_ws;
  __hip_bfloat16* xl = xh + (size_t)M_DIM * K_DIM;
  float* rowsum = (float*)(xl + (size_t)M_DIM * K_DIM);

  prep_split<<<128, 256, 0, stream>>>(x, xh, xl);
  rowsum_k<<<64, 256, 0, stream>>>(x, rowsum);
  wqmm<<<N_DIM / TN, 256, 0, stream>>>(W, xh, xl, rowsum, scale, offset, bias,
                                       out);
}